// Round 1
// baseline (566.703 us; speedup 1.0000x reference)
//
#include <hip/hip_runtime.h>
#include <math.h>

#define T_SEQ 4096
#define C_DIM 1024
#define H_DIM 64
#define B_SZ  4
#define KVB   16

// ---------------- QKV projection: Y[M,64] = X[M,1024] @ W[1024,64] ----------------
// grid (M/64, 3), block 256. fp32 tiled GEMM, BK=32.
__global__ __launch_bounds__(256) void qkv_gemm_kernel(
    const float* __restrict__ x,
    const float* __restrict__ Wq,
    const float* __restrict__ Wk,
    const float* __restrict__ Wv,
    float* __restrict__ qb,
    float* __restrict__ kb,
    float* __restrict__ vb)
{
    const int m0  = blockIdx.x * 64;
    const int sel = blockIdx.y;
    const float* W = (sel == 0) ? Wq : ((sel == 1) ? Wk : Wv);
    float*       Y = (sel == 0) ? qb : ((sel == 1) ? kb : vb);

    __shared__ float Xs[64][33];   // +1 pad: a-reads are row-strided
    __shared__ float Ws[32][64];

    const int t  = threadIdx.x;
    const int tx = t & 15;         // output col group (4 cols)
    const int ty = t >> 4;         // output row group (4 rows)

    float acc[4][4] = {{0.f,0.f,0.f,0.f},{0.f,0.f,0.f,0.f},{0.f,0.f,0.f,0.f},{0.f,0.f,0.f,0.f}};

    for (int k0 = 0; k0 < C_DIM; k0 += 32) {
        #pragma unroll
        for (int i = 0; i < 8; ++i) {
            int idx = t + 256 * i;            // 0..2047
            int r = idx >> 5, c = idx & 31;
            Xs[r][c] = x[(size_t)(m0 + r) * C_DIM + (k0 + c)];
        }
        #pragma unroll
        for (int i = 0; i < 8; ++i) {
            int idx = t + 256 * i;            // 0..2047
            int r = idx >> 6, c = idx & 63;
            Ws[r][c] = W[(size_t)(k0 + r) * H_DIM + c];
        }
        __syncthreads();
        #pragma unroll
        for (int kk = 0; kk < 32; ++kk) {
            float a0 = Xs[ty*4+0][kk];
            float a1 = Xs[ty*4+1][kk];
            float a2 = Xs[ty*4+2][kk];
            float a3 = Xs[ty*4+3][kk];
            float4 b4 = *(const float4*)&Ws[kk][tx*4];
            acc[0][0] += a0*b4.x; acc[0][1] += a0*b4.y; acc[0][2] += a0*b4.z; acc[0][3] += a0*b4.w;
            acc[1][0] += a1*b4.x; acc[1][1] += a1*b4.y; acc[1][2] += a1*b4.z; acc[1][3] += a1*b4.w;
            acc[2][0] += a2*b4.x; acc[2][1] += a2*b4.y; acc[2][2] += a2*b4.z; acc[2][3] += a2*b4.w;
            acc[3][0] += a3*b4.x; acc[3][1] += a3*b4.y; acc[3][2] += a3*b4.z; acc[3][3] += a3*b4.w;
        }
        __syncthreads();
    }
    #pragma unroll
    for (int i = 0; i < 4; ++i) {
        float4 o = make_float4(acc[i][0], acc[i][1], acc[i][2], acc[i][3]);
        *(float4*)&Y[(size_t)(m0 + ty*4 + i) * H_DIM + tx*4] = o;
    }
}

// ---------------- Causal flash attention ----------------
// grid (T/64, B), block 256 (4 waves). Lane owns one q-row; waves split the
// KV range 4-ways (j % 4 == w) with private 16-row K/V LDS tiles (wave-uniform
// broadcast reads), per-lane online softmax, 4-way merge at the end.
__global__ __launch_bounds__(256) void attn_kernel(
    const float* __restrict__ qb,
    const float* __restrict__ kb,
    const float* __restrict__ vb,
    float* __restrict__ out)
{
    __shared__ float smem[16384];        // exactly 64 KB
    float* qs = smem;                    // [64][64]
    float* ks = smem + 4096;             // [4][16][64]
    float* vs = smem + 8192;             // [4][16][64]
    float* sl = smem + 12288;            // [4][16][64] per-lane score spill

    const int qtile = blockIdx.x;
    const int b     = blockIdx.y;
    const int qbase = qtile * 64;
    const int t     = threadIdx.x;
    const int w     = t >> 6;
    const int lane  = t & 63;
    const int row   = qbase + lane;

    const float* Q = qb + (size_t)b * T_SEQ * H_DIM;
    const float* K = kb + (size_t)b * T_SEQ * H_DIM;
    const float* V = vb + (size_t)b * T_SEQ * H_DIM;

    // stage Q tile coalesced, then pull own row to registers
    #pragma unroll
    for (int i = 0; i < 4; ++i) {
        int idx4 = t + 256 * i;          // float4 index 0..1023
        *(float4*)&qs[idx4 * 4] = *(const float4*)&Q[(size_t)qbase * H_DIM + idx4 * 4];
    }
    __syncthreads();

    float4 q4[16];
    #pragma unroll
    for (int j = 0; j < 16; ++j) q4[j] = *(float4*)&qs[lane * 64 + j * 4];

    float4 o4[16];
    #pragma unroll
    for (int j = 0; j < 16; ++j) o4[j] = make_float4(0.f, 0.f, 0.f, 0.f);
    float m = -1e30f, l = 0.f;

    float* ksw = ks + w * (KVB * 64);
    float* vsw = vs + w * (KVB * 64);
    float* slw = sl + w * (KVB * 64);

    const int lastTile = (qbase + 63) >> 4;      // inclusive; = 4*qtile+3
    for (int j = w; j <= lastTile; j += 4) {
        const int jbase = j << 4;
        const float* Ksrc = K + (size_t)jbase * H_DIM;
        const float* Vsrc = V + (size_t)jbase * H_DIM;
        #pragma unroll
        for (int i = 0; i < 4; ++i) {
            int off = (lane + 64 * i) * 4;       // float offset 0..1020
            *(float4*)&ksw[off] = *(const float4*)&Ksrc[off];
            *(float4*)&vsw[off] = *(const float4*)&Vsrc[off];
        }
        asm volatile("s_waitcnt lgkmcnt(0)" ::: "memory");   // cross-lane LDS visibility (same wave)
        if (row >= jbase) {
            // pass 1: scores + tile max (dynamic jj loop; s spilled to LDS, not regs)
            float smax = -1e30f;
            for (int jj = 0; jj < KVB; ++jj) {
                const float4* kr = (const float4*)&ksw[jj * 64];
                float ax = 0.f, ay = 0.f, az = 0.f, aw = 0.f;
                #pragma unroll
                for (int d4 = 0; d4 < 16; ++d4) {
                    float4 kv = kr[d4];          // wave-uniform broadcast read
                    ax += q4[d4].x * kv.x;
                    ay += q4[d4].y * kv.y;
                    az += q4[d4].z * kv.z;
                    aw += q4[d4].w * kv.w;
                }
                float s = ((ax + ay) + (az + aw)) * 0.03125f;   // * C^-0.5
                s = (jbase + jj <= row) ? s : -1e30f;           // causal mask
                slw[jj * 64 + lane] = s;
                smax = fmaxf(smax, s);
            }
            float mnew   = fmaxf(m, smax);
            float factor = __expf(m - mnew);
            m = mnew;
            l *= factor;
            #pragma unroll
            for (int d4 = 0; d4 < 16; ++d4) {
                o4[d4].x *= factor; o4[d4].y *= factor;
                o4[d4].z *= factor; o4[d4].w *= factor;
            }
            asm volatile("s_waitcnt lgkmcnt(0)" ::: "memory");
            // pass 2: p = exp(s-m), accumulate l and O += p * V
            for (int jj = 0; jj < KVB; ++jj) {
                float p = __expf(slw[jj * 64 + lane] - m);      // masked -> exp(-1e30)=0
                l += p;
                const float4* vr = (const float4*)&vsw[jj * 64];
                #pragma unroll
                for (int d4 = 0; d4 < 16; ++d4) {
                    float4 vv = vr[d4];          // wave-uniform broadcast read
                    o4[d4].x += p * vv.x;
                    o4[d4].y += p * vv.y;
                    o4[d4].z += p * vv.z;
                    o4[d4].w += p * vv.w;
                }
            }
        }
    }

    // ---- merge the 4 per-wave partials (two d-halves to fit 64 KB LDS) ----
    __syncthreads();
    float* o_half = smem;            // [4][64][32]
    float* mlb    = smem + 8192;     // m: [0..255], l: [256..511]

    #pragma unroll
    for (int d4 = 0; d4 < 8; ++d4)
        *(float4*)&o_half[(w * 64 + lane) * 32 + d4 * 4] = o4[d4];
    mlb[w * 64 + lane]       = m;
    mlb[256 + w * 64 + lane] = l;
    __syncthreads();

    const int r    = t >> 2;
    const int dseg = t & 3;
    float m0_ = mlb[r],       m1_ = mlb[64 + r],  m2_ = mlb[128 + r], m3_ = mlb[192 + r];
    float l0_ = mlb[256 + r], l1_ = mlb[320 + r], l2_ = mlb[384 + r], l3_ = mlb[448 + r];
    float M  = fmaxf(fmaxf(m0_, m1_), fmaxf(m2_, m3_));
    float e0 = __expf(m0_ - M), e1 = __expf(m1_ - M), e2 = __expf(m2_ - M), e3 = __expf(m3_ - M);
    float L  = l0_ * e0 + l1_ * e1 + l2_ * e2 + l3_ * e3;
    float invL = 1.0f / L;
    float* orow = out + ((size_t)b * T_SEQ + qbase + r) * H_DIM;

    #pragma unroll
    for (int i = 0; i < 2; ++i) {
        int d = dseg * 8 + i * 4;
        float4 a0 = *(float4*)&o_half[(0 * 64 + r) * 32 + d];
        float4 a1 = *(float4*)&o_half[(1 * 64 + r) * 32 + d];
        float4 a2 = *(float4*)&o_half[(2 * 64 + r) * 32 + d];
        float4 a3 = *(float4*)&o_half[(3 * 64 + r) * 32 + d];
        float4 res;
        res.x = (a0.x*e0 + a1.x*e1 + a2.x*e2 + a3.x*e3) * invL;
        res.y = (a0.y*e0 + a1.y*e1 + a2.y*e2 + a3.y*e3) * invL;
        res.z = (a0.z*e0 + a1.z*e1 + a2.z*e2 + a3.z*e3) * invL;
        res.w = (a0.w*e0 + a1.w*e1 + a2.w*e2 + a3.w*e3) * invL;
        *(float4*)&orow[d] = res;
    }

    __syncthreads();
    #pragma unroll
    for (int d4 = 0; d4 < 8; ++d4)
        *(float4*)&o_half[(w * 64 + lane) * 32 + d4 * 4] = o4[8 + d4];
    __syncthreads();
    #pragma unroll
    for (int i = 0; i < 2; ++i) {
        int d = dseg * 8 + i * 4;
        float4 a0 = *(float4*)&o_half[(0 * 64 + r) * 32 + d];
        float4 a1 = *(float4*)&o_half[(1 * 64 + r) * 32 + d];
        float4 a2 = *(float4*)&o_half[(2 * 64 + r) * 32 + d];
        float4 a3 = *(float4*)&o_half[(3 * 64 + r) * 32 + d];
        float4 res;
        res.x = (a0.x*e0 + a1.x*e1 + a2.x*e2 + a3.x*e3) * invL;
        res.y = (a0.y*e0 + a1.y*e1 + a2.y*e2 + a3.y*e3) * invL;
        res.z = (a0.z*e0 + a1.z*e1 + a2.z*e2 + a3.z*e3) * invL;
        res.w = (a0.w*e0 + a1.w*e1 + a2.w*e2 + a3.w*e3) * invL;
        *(float4*)&orow[32 + d] = res;
    }
}

extern "C" void kernel_launch(void* const* d_in, const int* in_sizes, int n_in,
                              void* d_out, int out_size, void* d_ws, size_t ws_size,
                              hipStream_t stream)
{
    // setup_inputs order: x, Wk, Wq, Wv
    const float* x  = (const float*)d_in[0];
    const float* Wk = (const float*)d_in[1];
    const float* Wq = (const float*)d_in[2];
    const float* Wv = (const float*)d_in[3];
    float* outp = (float*)d_out;

    const size_t MH = (size_t)B_SZ * T_SEQ * H_DIM;   // 1,048,576 elems
    float* qbuf = (float*)d_ws;                        // 12 MB total scratch
    float* kbuf = qbuf + MH;
    float* vbuf = kbuf + MH;

    qkv_gemm_kernel<<<dim3((B_SZ * T_SEQ) / 64, 3), 256, 0, stream>>>(
        x, Wq, Wk, Wv, qbuf, kbuf, vbuf);
    attn_kernel<<<dim3(T_SEQ / 64, B_SZ), 256, 0, stream>>>(
        qbuf, kbuf, vbuf, outp);
}

// Round 2
// 150.278 us; speedup vs baseline: 3.7710x; 3.7710x over previous
//
#include <hip/hip_runtime.h>
#include <math.h>

typedef short bfx8 __attribute__((ext_vector_type(8)));
typedef short bfx4 __attribute__((ext_vector_type(4)));
typedef float fx4  __attribute__((ext_vector_type(4)));

__device__ __forceinline__ unsigned short f2bf(float f) {
    unsigned int u = __builtin_bit_cast(unsigned int, f);
    u += 0x7FFFu + ((u >> 16) & 1u);        // round-to-nearest-even
    return (unsigned short)(u >> 16);
}

// ---------- Wt prep: wt[192][1024] bf16 = [Wq;Wk;Wv]^T ----------
__global__ __launch_bounds__(256) void wt_prep(const float* __restrict__ Wq,
                                               const float* __restrict__ Wk,
                                               const float* __restrict__ Wv,
                                               unsigned short* __restrict__ wt)
{
    const int n = blockIdx.x;                 // 0..191
    const float* W = (n < 64) ? Wq : ((n < 128) ? Wk : Wv);
    const int nn = n & 63;
    const int t = threadIdx.x;
    #pragma unroll
    for (int i = 0; i < 4; ++i) {
        int k = t + 256 * i;
        wt[(size_t)n * 1024 + k] = f2bf(W[(size_t)k * 64 + nn]);
    }
}

// ---------- QKV: Y[16384,192] = X[16384,1024] @ Wt^T, MFMA bf16 ----------
// grid 256, block 256 (4 waves, 16 rows each). v written transposed to vt[b][d][t].
__global__ __launch_bounds__(256) void qkv_mfma(
    const float* __restrict__ x, const unsigned short* __restrict__ wt,
    unsigned short* __restrict__ qb, unsigned short* __restrict__ kb,
    unsigned short* __restrict__ vt)
{
    __shared__ unsigned short Xs[64 * 64];    // swizzled [m][k]
    __shared__ unsigned short Ws[192 * 64];   // swizzled [n][k]
    char* XsB = (char*)Xs;
    char* WsB = (char*)Ws;

    const int t = threadIdx.x;
    const int w = t >> 6, l = t & 63, g = l >> 4, li = l & 15;
    const int m0 = blockIdx.x * 64;

    fx4 acc[12];
    #pragma unroll
    for (int i = 0; i < 12; ++i) acc[i] = (fx4){0.f, 0.f, 0.f, 0.f};

    for (int k0 = 0; k0 < 1024; k0 += 64) {
        __syncthreads();
        #pragma unroll
        for (int i = 0; i < 4; ++i) {         // stage X (fp32 -> bf16)
            int idx = t + 256 * i;            // 0..1023 float4 units
            int r = idx >> 4, c4 = idx & 15;
            const float4 xv = *(const float4*)&x[(size_t)(m0 + r) * 1024 + k0 + c4 * 4];
            bfx4 o;
            o[0] = (short)f2bf(xv.x); o[1] = (short)f2bf(xv.y);
            o[2] = (short)f2bf(xv.z); o[3] = (short)f2bf(xv.w);
            *(bfx4*)(XsB + ((r * 128 + c4 * 8) ^ ((r & 7) << 4))) = o;
        }
        #pragma unroll
        for (int i = 0; i < 6; ++i) {         // stage Wt
            int idx = t + 256 * i;            // 0..1535 16B units
            int n = idx >> 3, c = idx & 7;
            bfx8 wv = *(const bfx8*)&wt[(size_t)n * 1024 + k0 + c * 8];
            *(bfx8*)(WsB + ((n * 128 + c * 16) ^ ((n & 7) << 4))) = wv;
        }
        __syncthreads();
        #pragma unroll
        for (int kk = 0; kk < 2; ++kk) {
            const int arow = w * 16 + li;
            bfx8 af = *(bfx8*)(XsB + ((arow * 128 + kk * 64 + g * 16) ^ ((arow & 7) << 4)));
            #pragma unroll
            for (int nb = 0; nb < 12; ++nb) {
                int nrow = nb * 16 + li;
                bfx8 bf = *(bfx8*)(WsB + ((nrow * 128 + kk * 64 + g * 16) ^ ((nrow & 7) << 4)));
                acc[nb] = __builtin_amdgcn_mfma_f32_16x16x32_bf16(af, bf, acc[nb], 0, 0, 0);
            }
        }
    }

    const int mrow = m0 + w * 16 + g * 4;     // + r ; D: row=(l>>4)*4+r, col=l&15
    #pragma unroll
    for (int nb = 0; nb < 4; ++nb) {          // q, with C^-0.5 folded in
        #pragma unroll
        for (int r = 0; r < 4; ++r)
            qb[(size_t)(mrow + r) * 64 + nb * 16 + li] = f2bf(acc[nb][r] * 0.03125f);
    }
    #pragma unroll
    for (int nb = 4; nb < 8; ++nb) {          // k
        #pragma unroll
        for (int r = 0; r < 4; ++r)
            kb[(size_t)(mrow + r) * 64 + (nb - 4) * 16 + li] = f2bf(acc[nb][r]);
    }

    __syncthreads();                           // reuse Xs for v transpose
    #pragma unroll
    for (int nb = 8; nb < 12; ++nb) {
        #pragma unroll
        for (int r = 0; r < 4; ++r)
            Xs[((nb - 8) * 16 + li) * 64 + (w * 16 + g * 4 + r)] = f2bf(acc[nb][r]);
    }
    __syncthreads();
    const int bb = m0 >> 12, mt = m0 & 4095;
    #pragma unroll
    for (int i = 0; i < 2; ++i) {
        int idx = t + 256 * i;
        int d = idx >> 3, c = idx & 7;
        *(bfx8*)&vt[((size_t)(bb * 64 + d)) * 4096 + mt + c * 8] = *(bfx8*)&Xs[d * 64 + c * 8];
    }
}

// ---------- MFMA flash attention (swapped QK^T, O^T accumulate) ----------
// grid (128,4), block 256 (4 waves). Wave: qsub = w&1 (16 rows), kv-parity = w>>1.
__global__ __launch_bounds__(256) void attn_mfma(
    const unsigned short* __restrict__ qb, const unsigned short* __restrict__ kb,
    const unsigned short* __restrict__ vt, float* __restrict__ out)
{
    __shared__ unsigned short smem[10240];    // 20 KB
    char* QsB = (char*)smem;                  // 4 KB  [32][64] swizzled
    char* KsB = QsB + 4096;                   // 8 KB  [64][64] swizzled
    char* VsB = QsB + 12288;                  // 8 KB  V^T [d][kv] swizzled

    const int t = threadIdx.x;
    const int w = t >> 6, l = t & 63, g = l >> 4, li = l & 15;
    const int qt = 127 - blockIdx.x;          // long tiles dispatch first
    const int b  = blockIdx.y;
    const int qbase = qt * 32;
    const int qsub = w & 1, par = w >> 1;

    const unsigned short* Qg = qb + (size_t)b * 4096 * 64;
    const unsigned short* Kg = kb + (size_t)b * 4096 * 64;
    const unsigned short* Vg = vt + (size_t)b * 64 * 4096;

    {   // stage Q tile (32x64)
        int r = t >> 3, c = t & 7;
        bfx8 v = *(const bfx8*)&Qg[(size_t)(qbase + r) * 64 + c * 8];
        *(bfx8*)(QsB + ((r * 128 + c * 16) ^ ((r & 7) << 4))) = v;
    }
    __syncthreads();

    const int qrow  = qsub * 16 + li;
    const int qglob = qbase + qrow;
    const bfx8 qf0 = *(bfx8*)(QsB + ((qrow * 128 + 0  + g * 16) ^ ((qrow & 7) << 4)));
    const bfx8 qf1 = *(bfx8*)(QsB + ((qrow * 128 + 64 + g * 16) ^ ((qrow & 7) << 4)));
    const int qmaxr = qbase + qsub * 16 + 15;

    fx4 o0 = {0,0,0,0}, o1 = {0,0,0,0}, o2 = {0,0,0,0}, o3 = {0,0,0,0};
    float m = -1e30f, lsum = 0.f;

    const int nch = (qt >> 1) + 1;
    for (int ch = 0; ch < nch; ++ch) {
        const int cb = ch * 64;
        __syncthreads();
        #pragma unroll
        for (int i = 0; i < 2; ++i) {         // stage K chunk [64][64]
            int idx = t + 256 * i;
            int r = idx >> 3, c = idx & 7;
            bfx8 kv = *(const bfx8*)&Kg[(size_t)(cb + r) * 64 + c * 8];
            *(bfx8*)(KsB + ((r * 128 + c * 16) ^ ((r & 7) << 4))) = kv;
        }
        #pragma unroll
        for (int i = 0; i < 2; ++i) {         // stage V^T chunk [64 d][64 kv]
            int idx = t + 256 * i;
            int d = idx >> 3, c = idx & 7;
            bfx8 vv = *(const bfx8*)&Vg[(size_t)d * 4096 + cb + c * 8];
            *(bfx8*)(VsB + ((d * 128 + c * 16) ^ ((d & 7) << 4))) = vv;
        }
        __syncthreads();

        const int sub = cb + par * 32;
        if (sub <= qmaxr) {                   // wave-uniform
            const int k0 = par * 32;
            fx4 s0 = {0,0,0,0}, s1 = {0,0,0,0};
            {
                const int kr = k0 + li;
                bfx8 kf0 = *(bfx8*)(KsB + ((kr * 128 + 0  + g * 16) ^ ((kr & 7) << 4)));
                bfx8 kf1 = *(bfx8*)(KsB + ((kr * 128 + 64 + g * 16) ^ ((kr & 7) << 4)));
                s0 = __builtin_amdgcn_mfma_f32_16x16x32_bf16(kf0, qf0, s0, 0, 0, 0);
                s0 = __builtin_amdgcn_mfma_f32_16x16x32_bf16(kf1, qf1, s0, 0, 0, 0);
            }
            {
                const int kr = k0 + 16 + li;
                bfx8 kf0 = *(bfx8*)(KsB + ((kr * 128 + 0  + g * 16) ^ ((kr & 7) << 4)));
                bfx8 kf1 = *(bfx8*)(KsB + ((kr * 128 + 64 + g * 16) ^ ((kr & 7) << 4)));
                s1 = __builtin_amdgcn_mfma_f32_16x16x32_bf16(kf0, qf0, s1, 0, 0, 0);
                s1 = __builtin_amdgcn_mfma_f32_16x16x32_bf16(kf1, qf1, s1, 0, 0, 0);
            }
            // lane holds S^T[kv = sub + {4g+r, 16+4g+r}][q = qglob]
            float p[8];
            float smax = -1e30f;
            #pragma unroll
            for (int r = 0; r < 4; ++r) {
                bool ok0 = (sub + 4 * g + r)      <= qglob;
                bool ok1 = (sub + 16 + 4 * g + r) <= qglob;
                float v0 = ok0 ? s0[r] : -1e30f;
                float v1 = ok1 ? s1[r] : -1e30f;
                p[r] = v0; p[4 + r] = v1;
                smax = fmaxf(smax, fmaxf(v0, v1));
            }
            smax = fmaxf(smax, __shfl_xor(smax, 16));
            smax = fmaxf(smax, __shfl_xor(smax, 32));
            const float mnew = fmaxf(m, smax);
            const float fac = __expf(m - mnew);
            float ps = 0.f;
            #pragma unroll
            for (int e = 0; e < 8; ++e) {
                float pe = (p[e] > -1e29f) ? __expf(p[e] - mnew) : 0.f;
                p[e] = pe; ps += pe;
            }
            ps += __shfl_xor(ps, 16);
            ps += __shfl_xor(ps, 32);
            lsum = lsum * fac + ps;
            m = mnew;
            o0 *= fac; o1 *= fac; o2 *= fac; o3 *= fac;

            bfx8 pf;
            #pragma unroll
            for (int e = 0; e < 8; ++e) pf[e] = (short)f2bf(p[e]);

            const int cofs = par * 64;        // byte offset of this kv half
            #pragma unroll
            for (int dblk = 0; dblk < 4; ++dblk) {
                const int dr = dblk * 16 + li;
                bfx4 vlo = *(bfx4*)(VsB + ((dr * 128 + cofs + 8 * g)      ^ ((dr & 7) << 4)));
                bfx4 vhi = *(bfx4*)(VsB + ((dr * 128 + cofs + 32 + 8 * g) ^ ((dr & 7) << 4)));
                bfx8 vf;
                vf[0] = vlo[0]; vf[1] = vlo[1]; vf[2] = vlo[2]; vf[3] = vlo[3];
                vf[4] = vhi[0]; vf[5] = vhi[1]; vf[6] = vhi[2]; vf[7] = vhi[3];
                fx4& oo = (dblk == 0) ? o0 : ((dblk == 1) ? o1 : ((dblk == 2) ? o2 : o3));
                oo = __builtin_amdgcn_mfma_f32_16x16x32_bf16(vf, pf, oo, 0, 0, 0);
            }
        }
    }

    // ---- 2-way merge (wave w with w+2) ----
    __syncthreads();
    float* Osh = (float*)(QsB + 4096);        // 16 KB: [4 waves][16 q][64 d]
    float* msh = (float*)QsB;                 // m: [0..63], l: [64..127]
    #pragma unroll
    for (int dblk = 0; dblk < 4; ++dblk) {
        const fx4 oo = (dblk == 0) ? o0 : ((dblk == 1) ? o1 : ((dblk == 2) ? o2 : o3));
        #pragma unroll
        for (int r = 0; r < 4; ++r)
            Osh[(w * 16 + li) * 64 + dblk * 16 + g * 4 + r] = oo[r];
    }
    if (g == 0) { msh[w * 16 + li] = m; msh[64 + w * 16 + li] = lsum; }
    __syncthreads();

    const int q = t >> 3, dc = (t & 7) * 8;
    const int ql = q & 15, qs2 = q >> 4;
    const int wA = qs2, wB = qs2 + 2;
    const float mA = msh[wA * 16 + ql], mB = msh[wB * 16 + ql];
    const float lA = msh[64 + wA * 16 + ql], lB = msh[64 + wB * 16 + ql];
    const float M  = fmaxf(mA, mB);
    const float eA = __expf(mA - M), eB = __expf(mB - M);
    const float inv = 1.f / (lA * eA + lB * eB);
    float* orow = out + ((size_t)b * 4096 + qbase + q) * 64 + dc;
    const float* OA = &Osh[(wA * 16 + ql) * 64 + dc];
    const float* OB = &Osh[(wB * 16 + ql) * 64 + dc];
    #pragma unroll
    for (int j = 0; j < 8; ++j)
        orow[j] = (OA[j] * eA + OB[j] * eB) * inv;
}

extern "C" void kernel_launch(void* const* d_in, const int* in_sizes, int n_in,
                              void* d_out, int out_size, void* d_ws, size_t ws_size,
                              hipStream_t stream)
{
    // setup_inputs order: x, Wk, Wq, Wv
    const float* x  = (const float*)d_in[0];
    const float* Wk = (const float*)d_in[1];
    const float* Wq = (const float*)d_in[2];
    const float* Wv = (const float*)d_in[3];
    float* outp = (float*)d_out;

    unsigned short* qbuf = (unsigned short*)d_ws;        // [4][4096][64] bf16
    unsigned short* kbuf = qbuf + (1u << 20);            // [4][4096][64] bf16
    unsigned short* vtb  = kbuf + (1u << 20);            // [4][64][4096] bf16 (V^T)
    unsigned short* wtb  = vtb  + (1u << 20);            // [192][1024] bf16 (W^T)

    wt_prep<<<192, 256, 0, stream>>>(Wq, Wk, Wv, wtb);
    qkv_mfma<<<256, 256, 0, stream>>>(x, wtb, qbuf, kbuf, vtb);
    attn_mfma<<<dim3(128, 4), 256, 0, stream>>>(qbuf, kbuf, vtb, outp);
}

// Round 3
// 70.183 us; speedup vs baseline: 8.0747x; 2.1412x over previous
//
#include <hip/hip_runtime.h>
#include <math.h>

typedef short bfx8 __attribute__((ext_vector_type(8)));
typedef short bfx4 __attribute__((ext_vector_type(4)));
typedef float fx4  __attribute__((ext_vector_type(4)));

__device__ __forceinline__ unsigned short f2bf(float f) {
    unsigned int u = __builtin_bit_cast(unsigned int, f);
    u += 0x7FFFu + ((u >> 16) & 1u);        // round-to-nearest-even
    return (unsigned short)(u >> 16);
}

// ---------- Wt prep via LDS transpose: wt[192][1024] bf16 = [Wq*2^-5; Wk; Wv]^T ----------
// grid (16,3), block 256
__global__ __launch_bounds__(256) void wt_prep(const float* __restrict__ Wq,
                                               const float* __restrict__ Wk,
                                               const float* __restrict__ Wv,
                                               unsigned short* __restrict__ wt)
{
    const int k0  = blockIdx.x * 64;
    const int mat = blockIdx.y;
    const float* W = (mat == 0) ? Wq : ((mat == 1) ? Wk : Wv);
    const float scale = (mat == 0) ? 0.03125f : 1.0f;   // fold softmax scale into Wq (2^-5, exact)
    __shared__ unsigned short Ls[64 * 68];
    const int t = threadIdx.x;
    #pragma unroll
    for (int i = 0; i < 4; ++i) {
        int idx4 = t + 256 * i;               // 0..1023
        int r = idx4 >> 4, c4 = idx4 & 15;
        float4 v = *(const float4*)&W[(size_t)(k0 + r) * 64 + c4 * 4];
        Ls[r * 68 + c4 * 4 + 0] = f2bf(v.x * scale);
        Ls[r * 68 + c4 * 4 + 1] = f2bf(v.y * scale);
        Ls[r * 68 + c4 * 4 + 2] = f2bf(v.z * scale);
        Ls[r * 68 + c4 * 4 + 3] = f2bf(v.w * scale);
    }
    __syncthreads();
    #pragma unroll
    for (int i = 0; i < 2; ++i) {
        int u = t + 256 * i;                  // 0..511 bfx8 units
        int n = u >> 3, kc = u & 7;
        bfx8 o;
        #pragma unroll
        for (int j = 0; j < 8; ++j) o[j] = (short)Ls[(kc * 8 + j) * 68 + n];
        *(bfx8*)&wt[(size_t)(mat * 64 + n) * 1024 + k0 + kc * 8] = o;
    }
}

// ---------- QKV: Y[16384,192] = X[16384,1024] @ Wt^T, MFMA bf16, double-buffered ----------
__global__ __launch_bounds__(256) void qkv_mfma(
    const float* __restrict__ x, const unsigned short* __restrict__ wt,
    unsigned short* __restrict__ qb, unsigned short* __restrict__ kb,
    unsigned short* __restrict__ vt)
{
    __shared__ alignas(16) char smem[65536];  // X bufs @0,8192 (8KB); W bufs @16384,40960 (24KB)
    const int t = threadIdx.x;
    const int w = t >> 6, l = t & 63, g = l >> 4, li = l & 15;
    const int m0 = blockIdx.x * 64;

    fx4 acc[12];
    #pragma unroll
    for (int i = 0; i < 12; ++i) acc[i] = (fx4){0.f, 0.f, 0.f, 0.f};

    float4 xr[4]; bfx8 wr[6];

#define QKV_LOAD(K0) do { \
    _Pragma("unroll") for (int i_ = 0; i_ < 4; ++i_) { int idx4 = t + 256 * i_; int r_ = idx4 >> 4, c4 = idx4 & 15; \
        xr[i_] = *(const float4*)&x[(size_t)(m0 + r_) * 1024 + (K0) + c4 * 4]; } \
    _Pragma("unroll") for (int i_ = 0; i_ < 6; ++i_) { int idx = t + 256 * i_; int n_ = idx >> 3, c_ = idx & 7; \
        wr[i_] = *(const bfx8*)&wt[(size_t)n_ * 1024 + (K0) + c_ * 8]; } \
} while (0)

#define QKV_STORE(BI) do { \
    char* xb_ = smem + ((BI) ? 8192 : 0); \
    char* wb_ = smem + 16384 + ((BI) ? 24576 : 0); \
    _Pragma("unroll") for (int i_ = 0; i_ < 4; ++i_) { int idx4 = t + 256 * i_; int r_ = idx4 >> 4, c4 = idx4 & 15; \
        bfx4 o_; o_[0] = (short)f2bf(xr[i_].x); o_[1] = (short)f2bf(xr[i_].y); \
        o_[2] = (short)f2bf(xr[i_].z); o_[3] = (short)f2bf(xr[i_].w); \
        *(bfx4*)(xb_ + ((r_ * 128 + c4 * 8) ^ ((r_ & 7) << 4))) = o_; } \
    _Pragma("unroll") for (int i_ = 0; i_ < 6; ++i_) { int idx = t + 256 * i_; int n_ = idx >> 3, c_ = idx & 7; \
        *(bfx8*)(wb_ + ((n_ * 128 + c_ * 16) ^ ((n_ & 7) << 4))) = wr[i_]; } \
} while (0)

    QKV_LOAD(0); QKV_STORE(0);
    __syncthreads();

    for (int ch = 0; ch < 16; ++ch) {
        if (ch + 1 < 16) QKV_LOAD((ch + 1) * 64);   // issue early
        if (ch) __syncthreads();                     // buf[ch&1] ready
        char* xb = smem + ((ch & 1) ? 8192 : 0);
        char* wb = smem + 16384 + ((ch & 1) ? 24576 : 0);
        const int arow = w * 16 + li;
        #pragma unroll
        for (int kk = 0; kk < 2; ++kk) {
            bfx8 af = *(bfx8*)(xb + ((arow * 128 + kk * 64 + g * 16) ^ ((arow & 7) << 4)));
            #pragma unroll
            for (int nb = 0; nb < 12; ++nb) {
                int nrow = nb * 16 + li;
                bfx8 bf = *(bfx8*)(wb + ((nrow * 128 + kk * 64 + g * 16) ^ ((nrow & 7) << 4)));
                acc[nb] = __builtin_amdgcn_mfma_f32_16x16x32_bf16(af, bf, acc[nb], 0, 0, 0);
            }
        }
        if (ch + 1 < 16) QKV_STORE((ch + 1) & 1);   // write late (different buffer)
    }

    const int mrow = m0 + w * 16 + g * 4;           // D: row=(l>>4)*4+r, col=l&15
    #pragma unroll
    for (int nb = 0; nb < 4; ++nb)
        #pragma unroll
        for (int r = 0; r < 4; ++r)
            qb[(size_t)(mrow + r) * 64 + nb * 16 + li] = f2bf(acc[nb][r]);   // scale folded into Wq
    #pragma unroll
    for (int nb = 4; nb < 8; ++nb)
        #pragma unroll
        for (int r = 0; r < 4; ++r)
            kb[(size_t)(mrow + r) * 64 + (nb - 4) * 16 + li] = f2bf(acc[nb][r]);

    __syncthreads();                                 // reuse smem for V transpose
    unsigned short* Vt = (unsigned short*)smem;      // [64 d][64 m]
    #pragma unroll
    for (int nb = 8; nb < 12; ++nb)
        #pragma unroll
        for (int r = 0; r < 4; ++r)
            Vt[((nb - 8) * 16 + li) * 64 + (w * 16 + g * 4 + r)] = f2bf(acc[nb][r]);
    __syncthreads();
    const int bb = m0 >> 12, mt = m0 & 4095;
    #pragma unroll
    for (int i = 0; i < 2; ++i) {
        int idx = t + 256 * i;
        int d = idx >> 3, c = idx & 7;
        *(bfx8*)&vt[((size_t)(bb * 64 + d)) * 4096 + mt + c * 8] = *(bfx8*)&Vt[d * 64 + c * 8];
    }
}

// ---------- MFMA flash attention: KVB=128, double-buffered, defer-max ----------
// grid 512 (b fastest, long q-tiles first), block 256 (4 waves: qsub=w&1, par=w>>1).
__global__ __launch_bounds__(256) void attn_mfma(
    const unsigned short* __restrict__ qb, const unsigned short* __restrict__ kb,
    const unsigned short* __restrict__ vt, float* __restrict__ out)
{
    __shared__ alignas(16) char smem[69632]; // Q @0 (4KB); K bufs @4096,20480 (16KB); V bufs @36864,53248 (16KB)
    const int t = threadIdx.x;
    const int w = t >> 6, l = t & 63, g = l >> 4, li = l & 15;
    const int bx = blockIdx.x;
    const int b  = bx & 3;
    const int qt = 127 - (bx >> 2);
    const int qbase = qt * 32;
    const int qsub = w & 1, par = w >> 1;

    const unsigned short* Qg = qb + (size_t)b * 4096 * 64;
    const unsigned short* Kg = kb + (size_t)b * 4096 * 64;
    const unsigned short* Vg = vt + (size_t)b * 64 * 4096;

    const int nch = (qbase + 32 + 127) >> 7;

    bfx8 krg[4], vrg[4];

#define ATT_LOAD(CB) do { \
    _Pragma("unroll") for (int i_ = 0; i_ < 4; ++i_) { int idx = t + 256 * i_; int r_ = idx >> 3, c_ = idx & 7; \
        krg[i_] = *(const bfx8*)&Kg[(size_t)((CB) + r_) * 64 + c_ * 8]; } \
    _Pragma("unroll") for (int i_ = 0; i_ < 4; ++i_) { int idx = t + 256 * i_; int d_ = idx >> 4, c_ = idx & 15; \
        vrg[i_] = *(const bfx8*)&Vg[(size_t)d_ * 4096 + (CB) + c_ * 8]; } \
} while (0)

#define ATT_STORE(BI) do { \
    char* kb_ = smem + 4096 + ((BI) ? 16384 : 0); \
    char* vb_ = smem + 36864 + ((BI) ? 16384 : 0); \
    _Pragma("unroll") for (int i_ = 0; i_ < 4; ++i_) { int idx = t + 256 * i_; int r_ = idx >> 3, c_ = idx & 7; \
        *(bfx8*)(kb_ + ((r_ * 128 + c_ * 16) ^ ((r_ & 7) << 4))) = krg[i_]; } \
    _Pragma("unroll") for (int i_ = 0; i_ < 4; ++i_) { int idx = t + 256 * i_; int d_ = idx >> 4, c_ = idx & 15; \
        *(bfx8*)(vb_ + ((d_ * 256 + c_ * 16) ^ ((d_ & 7) << 4))) = vrg[i_]; } \
} while (0)

    {   // stage Q tile [32][64]
        int r2 = t >> 3, c2 = t & 7;
        bfx8 qv = *(const bfx8*)&Qg[(size_t)(qbase + r2) * 64 + c2 * 8];
        *(bfx8*)(smem + ((r2 * 128 + c2 * 16) ^ ((r2 & 7) << 4))) = qv;
    }
    ATT_LOAD(0); ATT_STORE(0);
    __syncthreads();

    const int qrow  = qsub * 16 + li;
    const int qglob = qbase + qrow;
    const bfx8 qf0 = *(bfx8*)(smem + ((qrow * 128 + g * 16)      ^ ((qrow & 7) << 4)));
    const bfx8 qf1 = *(bfx8*)(smem + ((qrow * 128 + 64 + g * 16) ^ ((qrow & 7) << 4)));
    const int qmaxr = qbase + qsub * 16 + 15;

    fx4 o[4];
    #pragma unroll
    for (int i = 0; i < 4; ++i) o[i] = (fx4){0.f, 0.f, 0.f, 0.f};
    float m = -1e30f, lsum = 0.f;

    for (int ch = 0; ch < nch; ++ch) {
        const int cb = ch << 7;
        if (ch + 1 < nch) ATT_LOAD(cb + 128);       // issue early
        if (ch) __syncthreads();
        char* ks = smem + 4096  + ((ch & 1) ? 16384 : 0);
        char* vs = smem + 36864 + ((ch & 1) ? 16384 : 0);
        const int sub = cb + par * 64;
        if (sub <= qmaxr) {                          // wave-uniform causal skip
            fx4 s[4];
            #pragma unroll
            for (int i = 0; i < 4; ++i) s[i] = (fx4){0.f, 0.f, 0.f, 0.f};
            #pragma unroll
            for (int st = 0; st < 4; ++st) {
                int krow = par * 64 + st * 16 + li;
                int sw = (krow & 7) << 4;
                bfx8 kf0 = *(bfx8*)(ks + ((krow * 128 + g * 16)      ^ sw));
                bfx8 kf1 = *(bfx8*)(ks + ((krow * 128 + 64 + g * 16) ^ sw));
                s[st] = __builtin_amdgcn_mfma_f32_16x16x32_bf16(kf0, qf0, s[st], 0, 0, 0);
                s[st] = __builtin_amdgcn_mfma_f32_16x16x32_bf16(kf1, qf1, s[st], 0, 0, 0);
            }
            // S^T: lane (g,li) holds kv = sub + st*16 + 4g + rr, q = qglob
            float p[16]; float pmax = -1e30f;
            #pragma unroll
            for (int st = 0; st < 4; ++st)
                #pragma unroll
                for (int rr = 0; rr < 4; ++rr) {
                    int kv = sub + st * 16 + 4 * g + rr;
                    float vvv = (kv <= qglob) ? s[st][rr] : -1e30f;
                    p[st * 4 + rr] = vvv;
                    pmax = fmaxf(pmax, vvv);
                }
            pmax = fmaxf(pmax, __shfl_xor(pmax, 16));
            pmax = fmaxf(pmax, __shfl_xor(pmax, 32));
            if (__any(pmax > m + 8.f)) {            // defer-max (T13)
                float mnew = fmaxf(m, pmax);
                float fac = __expf(m - mnew);
                m = mnew; lsum *= fac;
                #pragma unroll
                for (int d2 = 0; d2 < 4; ++d2) {
                    o[d2][0] *= fac; o[d2][1] *= fac; o[d2][2] *= fac; o[d2][3] *= fac;
                }
            }
            float ps = 0.f;
            #pragma unroll
            for (int e = 0; e < 16; ++e) { p[e] = __expf(p[e] - m); ps += p[e]; }
            ps += __shfl_xor(ps, 16);
            ps += __shfl_xor(ps, 32);
            lsum += ps;
            bfx8 pf0, pf1;
            #pragma unroll
            for (int e = 0; e < 8; ++e) { pf0[e] = (short)f2bf(p[e]); pf1[e] = (short)f2bf(p[8 + e]); }
            #pragma unroll
            for (int dblk = 0; dblk < 4; ++dblk) {
                int dr = dblk * 16 + li;
                int base = dr * 256 + par * 128;
                int sw = (dr & 7) << 4;
                bfx4 a0 = *(bfx4*)(vs + ((base + 8 * g)      ^ sw));
                bfx4 a1 = *(bfx4*)(vs + ((base + 32 + 8 * g) ^ sw));
                bfx8 vf0;
                vf0[0] = a0[0]; vf0[1] = a0[1]; vf0[2] = a0[2]; vf0[3] = a0[3];
                vf0[4] = a1[0]; vf0[5] = a1[1]; vf0[6] = a1[2]; vf0[7] = a1[3];
                o[dblk] = __builtin_amdgcn_mfma_f32_16x16x32_bf16(vf0, pf0, o[dblk], 0, 0, 0);
                bfx4 b0 = *(bfx4*)(vs + ((base + 64 + 8 * g) ^ sw));
                bfx4 b1 = *(bfx4*)(vs + ((base + 96 + 8 * g) ^ sw));
                bfx8 vf1;
                vf1[0] = b0[0]; vf1[1] = b0[1]; vf1[2] = b0[2]; vf1[3] = b0[3];
                vf1[4] = b1[0]; vf1[5] = b1[1]; vf1[6] = b1[2]; vf1[7] = b1[3];
                o[dblk] = __builtin_amdgcn_mfma_f32_16x16x32_bf16(vf1, pf1, o[dblk], 0, 0, 0);
            }
        }
        if (ch + 1 < nch) ATT_STORE((ch + 1) & 1);  // write late (other buffer)
    }

    // ---- 2-way merge (wave w with w+2) ----
    __syncthreads();
    float* Osh = (float*)(smem + 4096);              // [4 waves][16 q][64 d]
    float* msh = (float*)smem;                       // m: [0..63], l: [64..127]
    #pragma unroll
    for (int dblk = 0; dblk < 4; ++dblk)
        #pragma unroll
        for (int r = 0; r < 4; ++r)
            Osh[(w * 16 + li) * 64 + dblk * 16 + g * 4 + r] = o[dblk][r];
    if (g == 0) { msh[w * 16 + li] = m; msh[64 + w * 16 + li] = lsum; }
    __syncthreads();

    const int q = t >> 3, dc = (t & 7) * 8;
    const int ql = q & 15, qs2 = q >> 4;
    const int wA = qs2, wB = qs2 + 2;
    const float mA = msh[wA * 16 + ql], mB = msh[wB * 16 + ql];
    const float lA = msh[64 + wA * 16 + ql], lB = msh[64 + wB * 16 + ql];
    const float M  = fmaxf(mA, mB);
    const float eA = __expf(mA - M), eB = __expf(mB - M);
    const float inv = 1.f / (lA * eA + lB * eB);
    float* orow = out + ((size_t)b * 4096 + qbase + q) * 64 + dc;
    const float* OA = &Osh[(wA * 16 + ql) * 64 + dc];
    const float* OB = &Osh[(wB * 16 + ql) * 64 + dc];
    #pragma unroll
    for (int j = 0; j < 8; ++j)
        orow[j] = (OA[j] * eA + OB[j] * eB) * inv;
}

extern "C" void kernel_launch(void* const* d_in, const int* in_sizes, int n_in,
                              void* d_out, int out_size, void* d_ws, size_t ws_size,
                              hipStream_t stream)
{
    // setup_inputs order: x, Wk, Wq, Wv
    const float* x  = (const float*)d_in[0];
    const float* Wk = (const float*)d_in[1];
    const float* Wq = (const float*)d_in[2];
    const float* Wv = (const float*)d_in[3];
    float* outp = (float*)d_out;

    unsigned short* qbuf = (unsigned short*)d_ws;        // [4][4096][64] bf16 (pre-scaled)
    unsigned short* kbuf = qbuf + (1u << 20);            // [4][4096][64] bf16
    unsigned short* vtb  = kbuf + (1u << 20);            // [4][64][4096] bf16 (V^T)
    unsigned short* wtb  = vtb  + (1u << 20);            // [192][1024] bf16 (W^T)

    wt_prep<<<dim3(16, 3), 256, 0, stream>>>(Wq, Wk, Wv, wtb);
    qkv_mfma<<<256, 256, 0, stream>>>(x, wtb, qbuf, kbuf, vtb);
    attn_mfma<<<512, 256, 0, stream>>>(qbuf, kbuf, vtb, outp);
}